// Round 2
// baseline (223.651 us; speedup 1.0000x reference)
//
#include <hip/hip_runtime.h>

// Output of the reference collapses to v = x @ Wv^T (T=1 makes the linear-
// attention read/scale cancel exactly: mem_read/scale = (sum qk)*v/(sum qk),
// and all qk terms are positive since elu+1>0 — no cancellation).
// So: one f32 GEMM, M=64 N=2048 K=2048.
//
// Layout: lane == batch (64 batches == 1 wave). Each block (1 wave)
// computes DPW=16 output columns (Wv rows) over a K/KSPLIT=128 slice.
// Wv addresses are uniform (blockIdx-derived) -> compiler emits s_load
// (scalar cache), costing zero VALU. x is packed to [k/4][b][4] so the
// wave's float4 loads are contiguous 1KB lines (L2-resident).
// Partial sums combine via atomicAdd onto memset-zeroed d_out.

#define NB    64
#define KDIM  2048
#define NDIM  2048
#define DPW   16
#define KSPLIT 16
#define KCHUNK (KDIM / KSPLIT)              // 128
#define NWAVES ((NDIM / DPW) * KSPLIT)      // 2048 blocks of 64 threads

__global__ __launch_bounds__(256)
void pack_x(const float* __restrict__ x, float* __restrict__ xp) {
    // x[b][k] -> xp[k>>2][b][k&3]; coalesced reads, L2-absorbed writes
    int tid = blockIdx.x * blockDim.x + threadIdx.x;  // = b*512 + k4
    int b  = tid >> 9;
    int k4 = tid & 511;
    float4 v = *(const float4*)(x + b * KDIM + (k4 << 2));
    *(float4*)(xp + ((size_t)k4 * NB + b) * 4) = v;
}

__global__ __launch_bounds__(64)
void gemv_v(const float* __restrict__ xsrc, const float* __restrict__ Wv,
            float* __restrict__ out, int sK4, int sL) {
    const int wave = blockIdx.x;     // uniform -> scalar Wv addressing
    const int lane = threadIdx.x;    // 0..63 == batch index
    const int ks = wave >> 7;        // 0..15  K-split slice
    const int dG = wave & 127;       // 0..127 d-group
    const int d0 = dG * DPW;
    const int k40 = (ks * KCHUNK) >> 2;

    float acc[DPW];
#pragma unroll
    for (int j = 0; j < DPW; ++j) acc[j] = 0.0f;

    const float* wbase = Wv + (size_t)d0 * KDIM;
#pragma unroll 2
    for (int k4 = k40; k4 < k40 + (KCHUNK >> 2); ++k4) {
        const float4 xv =
            *(const float4*)(xsrc + (size_t)k4 * sK4 + (size_t)lane * sL);
        const int kk = k4 << 2;
#pragma unroll
        for (int j = 0; j < DPW; ++j) {
            const float* w = wbase + (size_t)j * KDIM + kk;  // uniform -> s_load_dwordx4
            acc[j] = fmaf(xv.x, w[0], acc[j]);
            acc[j] = fmaf(xv.y, w[1], acc[j]);
            acc[j] = fmaf(xv.z, w[2], acc[j]);
            acc[j] = fmaf(xv.w, w[3], acc[j]);
        }
    }

    float* orow = out + (size_t)lane * NDIM + d0;
#pragma unroll
    for (int j = 0; j < DPW; ++j) atomicAdd(orow + j, acc[j]);
}

extern "C" void kernel_launch(void* const* d_in, const int* in_sizes, int n_in,
                              void* d_out, int out_size, void* d_ws, size_t ws_size,
                              hipStream_t stream) {
    const float* x  = (const float*)d_in[0];   // [64][2048]
    const float* Wv = (const float*)d_in[5];   // [2048][2048]
    float* out = (float*)d_out;                // [64][2048]

    hipMemsetAsync(out, 0, (size_t)NB * NDIM * sizeof(float), stream);

    const size_t packBytes = (size_t)NB * KDIM * sizeof(float);
    if (d_ws && ws_size >= packBytes) {
        float* xp = (float*)d_ws;
        pack_x<<<(NB * KDIM / 4) / 256, 256, 0, stream>>>(x, xp);
        // packed: offset = k4*256 + lane*4
        gemv_v<<<NWAVES, 64, 0, stream>>>(xp, Wv, out, NB * 4, 4);
    } else {
        // fallback: read x directly (strided but L2-cached)
        gemv_v<<<NWAVES, 64, 0, stream>>>(x, Wv, out, 4, KDIM);
    }
}

// Round 4
// 100.818 us; speedup vs baseline: 2.2184x; 2.2184x over previous
//
#include <hip/hip_runtime.h>

// out = x @ Wv^T  (the T=1 linear-attention read/scale cancels exactly;
// verified passing in round 2). M=64 N=2048 K=2048 f32.
//
// Design: lane = K. Each wave computes an 8-batch x 8-row output tile over
// the FULL K. Lane l owns k4 = {64*i + l}, i=0..7, so x[b][k4] and Wv[n][k4]
// float4 loads are coalesced (1KB/instr) in their ORIGINAL layouts — no pack
// kernel, no atomics, no memset. Per i-iter: 16 independent dwordx4 loads +
// 256 FMAs -> deep ILP. Cross-lane reduce via XOR-swizzled LDS (conflict-
// free), one dword store per lane.
//
// Grid: 256 n-octets x 2 b-halves = 512 blocks of 256 thr (4 waves = 4
// b-octets). Swizzle puts both b-halves of an n-octet on the SAME XCD
// (bid%8), so Wv is fetched from HBM once and the twin block hits L2.

#define ND 2048
#define KD 2048
#define K4 (KD / 4)  // 512

__global__ __launch_bounds__(256)
void vgemm(const float* __restrict__ x, const float* __restrict__ Wv,
           float* __restrict__ out) {
    const int lane = threadIdx.x & 63;
    const int wid  = threadIdx.x >> 6;   // 0..3
    const int bid  = blockIdx.x;
    // XCD-pair swizzle: blocks {h=0,1} of one n-octet land on the same XCD.
    const int nO   = (bid & 7) + ((bid >> 4) << 3);  // 0..255
    const int half = (bid >> 3) & 1;
    const int n0   = nO * 8;
    const int b0   = (half * 4 + wid) * 8;           // 0,8,...,56

    const float4* __restrict__ xq = (const float4*)x;   // idx = b*K4 + k4
    const float4* __restrict__ wq = (const float4*)Wv;  // idx = n*K4 + k4

    float acc[64];  // acc[bb*8+nn]
#pragma unroll
    for (int j = 0; j < 64; ++j) acc[j] = 0.0f;

#pragma unroll
    for (int i = 0; i < 8; ++i) {
        const int k4 = (i << 6) + lane;
        float4 xr[8], wr[8];
#pragma unroll
        for (int bb = 0; bb < 8; ++bb)
            xr[bb] = xq[(size_t)(b0 + bb) * K4 + k4];
#pragma unroll
        for (int nn = 0; nn < 8; ++nn)
            wr[nn] = wq[(size_t)(n0 + nn) * K4 + k4];
#pragma unroll
        for (int bb = 0; bb < 8; ++bb)
#pragma unroll
            for (int nn = 0; nn < 8; ++nn) {
                float a = acc[bb * 8 + nn];
                a = fmaf(xr[bb].x, wr[nn].x, a);
                a = fmaf(xr[bb].y, wr[nn].y, a);
                a = fmaf(xr[bb].z, wr[nn].z, a);
                a = fmaf(xr[bb].w, wr[nn].w, a);
                acc[bb * 8 + nn] = a;
            }
    }

    // Cross-lane reduce: lane j ends up with sum over all 64 lanes of acc[j].
    // XOR swizzle (column j ^ (lane&31)) -> every ds op is 2-way max (free).
    __shared__ float red[4][64][64];  // 64 KB -> 2 blocks/CU
    float* myrow = &red[wid][lane][0];
    const int swz = lane & 31;
#pragma unroll
    for (int j = 0; j < 64; ++j) myrow[j ^ swz] = acc[j];
    __syncthreads();

    float s = 0.0f;
#pragma unroll
    for (int l = 0; l < 64; ++l) s += red[wid][l][lane ^ (l & 31)];

    // acc index j=(bb*8+nn): lane j holds out[b0 + (j>>3)][n0 + (j&7)]
    out[(size_t)(b0 + (lane >> 3)) * ND + n0 + (lane & 7)] = s;
}

extern "C" void kernel_launch(void* const* d_in, const int* in_sizes, int n_in,
                              void* d_out, int out_size, void* d_ws, size_t ws_size,
                              hipStream_t stream) {
    const float* x  = (const float*)d_in[0];   // [64][2048]
    const float* Wv = (const float*)d_in[5];   // [2048][2048]
    float* out = (float*)d_out;                // [64][2048]

    vgemm<<<512, 256, 0, stream>>>(x, Wv, out);
}

// Round 6
// 99.560 us; speedup vs baseline: 2.2464x; 1.0126x over previous
//
#include <hip/hip_runtime.h>

// out = x @ Wv^T  (T=1 linear-attention read/scale cancels exactly; verified
// passing rounds 2 & 4). M=64 N=2048 K=2048 f32.
//
// lane = K outer-product scheme. Each wave: 8-batch x 8-row output tile over
// full K. The block's 8 Wv rows are a CONTIGUOUS 64KB region (row-major,
// consecutive rows) -> staged once per block into LDS and shared by all 4
// waves (was 4x-redundant global reads). Inner loop: 8 coalesced x float4
// loads (L2-resident) + 8 conflict-free ds_read_b128 + 256 FMAs.
// The cross-lane reduce scratch ALIASES the Wv LDS (barrier-separated), so
// LDS stays 64KB -> 2 blocks/CU -> 2 waves/SIMD.

#define ND 2048
#define KD 2048
#define K4 (KD / 4)  // 512

__global__ __launch_bounds__(256)
void vgemm(const float* __restrict__ x, const float* __restrict__ Wv,
           float* __restrict__ out) {
    __shared__ float wlds[8 * KD];       // 64KB; [nn][k] then reused as reduce
    const int tid  = threadIdx.x;
    const int lane = tid & 63;
    const int wid  = tid >> 6;           // 0..3
    const int bid  = blockIdx.x;
    // XCD-pair swizzle: both b-halves of one n-octet land on the same XCD.
    const int nO   = (bid & 7) + ((bid >> 4) << 3);  // 0..255
    const int half = (bid >> 3) & 1;
    const int n0   = nO * 8;
    const int b0   = (half * 4 + wid) * 8;           // 0,8,...,56

    // ---- stage the contiguous 64KB Wv tile into LDS (cooperative) ----
    const float4* __restrict__ wsrc = (const float4*)(Wv + (size_t)n0 * KD);
    float4* wdst = (float4*)wlds;        // 4096 float4
#pragma unroll
    for (int j = 0; j < 16; ++j) {
        const int idx = j * 256 + tid;   // coalesced 4KB chunks
        wdst[idx] = wsrc[idx];
    }
    __syncthreads();

    const float4* __restrict__ xq = (const float4*)x;    // idx = b*K4 + k4
    const float4* __restrict__ wl = (const float4*)wlds; // idx = nn*K4 + k4

    float acc[64];  // acc[bb*8+nn]
#pragma unroll
    for (int j = 0; j < 64; ++j) acc[j] = 0.0f;

#pragma unroll
    for (int i = 0; i < 8; ++i) {
        const int k4 = (i << 6) + lane;
        float4 xr[8], wr[8];
#pragma unroll
        for (int bb = 0; bb < 8; ++bb)
            xr[bb] = xq[(size_t)(b0 + bb) * K4 + k4];
#pragma unroll
        for (int nn = 0; nn < 8; ++nn)
            wr[nn] = wl[nn * K4 + k4];   // lane-contiguous ds_read_b128
#pragma unroll
        for (int bb = 0; bb < 8; ++bb)
#pragma unroll
            for (int nn = 0; nn < 8; ++nn) {
                float a = acc[bb * 8 + nn];
                a = fmaf(xr[bb].x, wr[nn].x, a);
                a = fmaf(xr[bb].y, wr[nn].y, a);
                a = fmaf(xr[bb].z, wr[nn].z, a);
                a = fmaf(xr[bb].w, wr[nn].w, a);
                acc[bb * 8 + nn] = a;
            }
    }

    // ---- cross-lane reduce; reuse wlds (all waves done reading W) ----
    __syncthreads();
    float (*red)[64][64] = (float (*)[64][64])wlds;  // wlds = 16384 floats
                                                     // = exactly [4][64][64]
    float* myrow = &red[wid][lane][0];
    const int swz = lane & 31;
#pragma unroll
    for (int j = 0; j < 64; ++j) myrow[j ^ swz] = acc[j];  // 2-way max: free
    __syncthreads();

    float s = 0.0f;
#pragma unroll
    for (int l = 0; l < 64; ++l) s += red[wid][l][lane ^ (l & 31)];

    // lane j holds out[b0 + (j>>3)][n0 + (j&7)]
    out[(size_t)(b0 + (lane >> 3)) * ND + n0 + (lane & 7)] = s;
}

extern "C" void kernel_launch(void* const* d_in, const int* in_sizes, int n_in,
                              void* d_out, int out_size, void* d_ws, size_t ws_size,
                              hipStream_t stream) {
    const float* x  = (const float*)d_in[0];   // [64][2048]
    const float* Wv = (const float*)d_in[5];   // [2048][2048]
    float* out = (float*)d_out;                // [64][2048]

    vgemm<<<512, 256, 0, stream>>>(x, Wv, out);
}